// Round 3
// baseline (1519.046 us; speedup 1.0000x reference)
//
#include <hip/hip_runtime.h>

#define N_NODES 200000
#define N_EDGES 6400000
#define IN_FEAT 128
#define HIDDEN  16

#define BNODES  512                      // nodes per bucket
#define NBUCK   391                      // ceil(N_NODES / BNODES)
#define GA      512                      // pass-A blocks
#define CHUNK   12500                    // edges per pass-A block (GA*CHUNK == N_EDGES)
#define SUB     2048                     // edges per LDS sub-sort
#define NSUB    7                        // ceil(CHUNK / SUB)

#define SCAN_LEN (NBUCK * GA)            // 200192
#define SCAN_B   256
#define NB_SCAN  ((SCAN_LEN + SCAN_B - 1) / SCAN_B)   // 782

// ---------------- fused degree count + coarse histogram ----------------

__global__ __launch_bounds__(256) void k_count_hist(const int* __restrict__ col,
                                                    unsigned* __restrict__ cnt,
                                                    unsigned* __restrict__ histg) {
    __shared__ unsigned bh[NBUCK];
    for (int i = threadIdx.x; i < NBUCK; i += 256) bh[i] = 0u;
    __syncthreads();
    const int base = blockIdx.x * CHUNK;
    for (int j = 0; j < CHUNK; j += 256) {
        int idx = j + threadIdx.x;
        if (idx < CHUNK) {
            int c = col[base + idx];
            atomicAdd(&cnt[c], 1u);
            atomicAdd(&bh[c >> 9], 1u);
        }
    }
    __syncthreads();
    for (int b = threadIdx.x; b < NBUCK; b += 256)
        histg[(size_t)b * GA + blockIdx.x] = bh[b];   // bucket-major for scan
}

__global__ void k_dinv(const unsigned* __restrict__ cnt, float* __restrict__ dinv) {
    int i = blockIdx.x * blockDim.x + threadIdx.x;
    if (i < N_NODES) dinv[i] = rsqrtf((float)cnt[i] + 1.0f);   // +1 self-loop
}

// ---------------- 2-level exclusive scan of histg (SCAN_LEN elements) ----------------

__global__ void k_scan1(unsigned* __restrict__ a, unsigned* __restrict__ part) {
    __shared__ unsigned s[SCAN_B];
    int i = blockIdx.x * SCAN_B + threadIdx.x;
    unsigned v = (i < SCAN_LEN) ? a[i] : 0u;
    s[threadIdx.x] = v;
    __syncthreads();
    for (int d = 1; d < SCAN_B; d <<= 1) {
        unsigned t = (threadIdx.x >= d) ? s[threadIdx.x - d] : 0u;
        __syncthreads();
        s[threadIdx.x] += t;
        __syncthreads();
    }
    if (i < SCAN_LEN) a[i] = s[threadIdx.x] - v;               // exclusive within block
    if (threadIdx.x == SCAN_B - 1) part[blockIdx.x] = s[threadIdx.x];
}

__global__ void k_scan2(unsigned* __restrict__ part) {
    __shared__ unsigned s[SCAN_B];
    __shared__ unsigned carry;
    if (threadIdx.x == 0) carry = 0u;
    __syncthreads();
    for (int base = 0; base < NB_SCAN; base += SCAN_B) {
        int i = base + threadIdx.x;
        unsigned v = (i < NB_SCAN) ? part[i] : 0u;
        s[threadIdx.x] = v;
        __syncthreads();
        for (int d = 1; d < SCAN_B; d <<= 1) {
            unsigned t = (threadIdx.x >= d) ? s[threadIdx.x - d] : 0u;
            __syncthreads();
            s[threadIdx.x] += t;
            __syncthreads();
        }
        if (i < NB_SCAN) part[i] = s[threadIdx.x] - v + carry;
        __syncthreads();
        if (threadIdx.x == 0) carry += s[SCAN_B - 1];
        __syncthreads();
    }
}

__global__ void k_scan3(unsigned* __restrict__ a, const unsigned* __restrict__ part) {
    int i = blockIdx.x * blockDim.x + threadIdx.x;
    if (i < SCAN_LEN) a[i] += part[i >> 8];
}

// ---------------- pass-A scatter: LDS sub-sort, bucket-contiguous u64 writes ----------------

__global__ __launch_bounds__(256) void kA_scat(const int* __restrict__ row,
                                               const int* __restrict__ col,
                                               const unsigned* __restrict__ histo,
                                               unsigned long long* __restrict__ tmp) {
    __shared__ unsigned basec[NBUCK];            // global cursor per bucket for this block
    __shared__ unsigned cntL[NBUCK];             // sub-chunk per-bucket counts
    __shared__ unsigned offL[2 * SCAN_B];        // padded inclusive scan
    __shared__ unsigned long long st[SUB];       // 16 KB staging
    const int tid = threadIdx.x;
    for (int b = tid; b < NBUCK; b += 256)
        basec[b] = histo[(size_t)b * GA + blockIdx.x];
    const int chunkBase = blockIdx.x * CHUNK;
    for (int sc = 0; sc < NSUB; ++sc) {
        const int subBase = sc * SUB;
        const int subCount = min(SUB, CHUNK - subBase);
        for (int b = tid; b < NBUCK; b += 256) cntL[b] = 0u;
        __syncthreads();
        unsigned long long pk[8]; unsigned bb[8]; unsigned rr[8]; int nv = 0;
        for (int j = 0; j < 8; ++j) {
            int li = j * 256 + tid;
            if (li < subCount) {
                int e = chunkBase + subBase + li;
                unsigned s = (unsigned)row[e];
                unsigned d = (unsigned)col[e];
                unsigned b = d >> 9;
                pk[nv] = ((unsigned long long)d << 32) | s;
                bb[nv] = b;
                rr[nv] = atomicAdd(&cntL[b], 1u);   // local rank
                ++nv;
            }
        }
        __syncthreads();
        offL[tid]       = (tid < NBUCK) ? cntL[tid] : 0u;
        offL[tid + 256] = (tid + 256 < NBUCK) ? cntL[tid + 256] : 0u;
        __syncthreads();
        for (int d = 1; d < 2 * SCAN_B; d <<= 1) {   // inclusive Hillis-Steele
            unsigned u0 = (tid >= d) ? offL[tid - d] : 0u;
            unsigned u1 = (tid + 256 >= d) ? offL[tid + 256 - d] : 0u;
            __syncthreads();
            offL[tid] += u0; offL[tid + 256] += u1;
            __syncthreads();
        }
        for (int j = 0; j < nv; ++j) {               // LDS scatter -> bucket-sorted
            unsigned b = bb[j];
            st[offL[b] - cntL[b] + rr[j]] = pk[j];
        }
        __syncthreads();
        for (int i = tid; i < subCount; i += 256) {  // bucket-contiguous global writes
            unsigned long long p = st[i];
            unsigned b = ((unsigned)(p >> 32)) >> 9;
            unsigned excl = offL[b] - cntL[b];
            tmp[(size_t)basec[b] + (unsigned)i - excl] = p;
        }
        __syncthreads();
        for (int b = tid; b < NBUCK; b += 256) basec[b] += cntL[b];
        __syncthreads();
    }
}

// ---------------- layer-1 GEMM: h = x @ W1 ----------------

__global__ __launch_bounds__(256) void k_gemm1(const float* __restrict__ x,
                                               const float* __restrict__ W1,
                                               float* __restrict__ h) {
    __shared__ float xs[16][132];
    __shared__ float ws[IN_FEAT * HIDDEN];
    const int tid = threadIdx.x;
    const int block_node = blockIdx.x * 16;
    for (int i = tid; i < IN_FEAT * HIDDEN; i += 256) ws[i] = W1[i];
    const int rows = min(16, N_NODES - block_node);
    const float4* x4 = (const float4*)(x + (size_t)block_node * IN_FEAT);
    for (int i = tid; i < rows * 32; i += 256) {
        float4 v = x4[i];
        int r = i >> 5, c = (i & 31) << 2;
        *(float4*)&xs[r][c] = v;
    }
    __syncthreads();
    const int n = tid >> 4, f = tid & 15;
    if (block_node + n < N_NODES) {
        float acc = 0.f;
        #pragma unroll 8
        for (int k = 0; k < IN_FEAT; ++k)
            acc = fmaf(xs[n][k], ws[k * HIDDEN + f], acc);
        h[(size_t)(block_node + n) * HIDDEN + f] = acc;
    }
}

// ---------------- layer-1 aggregate in LDS + fused bias/relu/W2 -> t ----------------
// One block per bucket. agg stride 17 breaks bank-conflict power-of-2.

__global__ __launch_bounds__(512) void kB1(const unsigned long long* __restrict__ tmp,
                                           const unsigned* __restrict__ histo,
                                           const float* __restrict__ dinv,
                                           const float* __restrict__ h,
                                           const float* __restrict__ b1,
                                           const float* __restrict__ W2,
                                           float* __restrict__ t) {
    __shared__ float agg[BNODES * 17];
    const int tid = threadIdx.x;
    const int b = blockIdx.x;
    const int baseNode = b * BNODES;
    for (int i = tid; i < BNODES * 17; i += 512) agg[i] = 0.f;
    const unsigned bstart = histo[(size_t)b * GA];
    const unsigned bend = (b == NBUCK - 1) ? N_EDGES : histo[(size_t)(b + 1) * GA];
    const int g = tid >> 4, f = tid & 15;
    const float b1f = b1[f], w2f = W2[f];
    __syncthreads();
    for (unsigned k = bstart + g; k < bend; k += 32) {
        unsigned long long p = tmp[k];
        unsigned s = (unsigned)p;
        unsigned dl = ((unsigned)(p >> 32)) & (BNODES - 1);
        float w = dinv[s];                            // 16-lane broadcast
        float hv = h[(size_t)s * HIDDEN + f];         // 64B contiguous per edge
        unsafeAtomicAdd(&agg[dl * 17 + f], w * hv);   // ds_add_f32
    }
    __syncthreads();
    for (int n = g; n < BNODES; n += 32) {
        int node = baseNode + n;
        if (node < N_NODES) {                         // uniform within 16-lane group
            float di = dinv[node];
            float pre = di * (agg[n * 17 + f] + di * h[(size_t)node * HIDDEN + f]);
            float r = fmaxf(pre + b1f, 0.f) * w2f;
            r += __shfl_xor(r, 8, 16);
            r += __shfl_xor(r, 4, 16);
            r += __shfl_xor(r, 2, 16);
            r += __shfl_xor(r, 1, 16);
            if (f == 0) t[node] = r;
        }
    }
}

// ---------------- layer 2: init + direct atomic scatter ----------------

__global__ void k_out_init(const float* __restrict__ dinv, const float* __restrict__ t,
                           const float* __restrict__ b2, float* __restrict__ out) {
    int i = blockIdx.x * blockDim.x + threadIdx.x;
    if (i < N_NODES) {
        float di = dinv[i];
        out[i] = fmaf(di * di, t[i], b2[0]);          // self-loop + bias
    }
}

__global__ void k_scatter2(const int* __restrict__ row, const int* __restrict__ col,
                           const float* __restrict__ dinv, const float* __restrict__ t,
                           float* __restrict__ out) {
    int e = blockIdx.x * blockDim.x + threadIdx.x;
    if (e < N_EDGES) {
        int r = row[e], c = col[e];
        unsafeAtomicAdd(&out[c], dinv[r] * dinv[c] * t[r]);
    }
}

// ---------------- launch ----------------

extern "C" void kernel_launch(void* const* d_in, const int* in_sizes, int n_in,
                              void* d_out, int out_size, void* d_ws, size_t ws_size,
                              hipStream_t stream) {
    const float* x   = (const float*)d_in[0];
    const int*   ei  = (const int*)d_in[1];
    const float* W1  = (const float*)d_in[2];
    const float* b1  = (const float*)d_in[3];
    const float* W2  = (const float*)d_in[4];
    const float* b2  = (const float*)d_in[5];
    float* out = (float*)d_out;

    const int* row = ei;               // sources
    const int* col = ei + N_EDGES;     // targets

    // ws: cnt u32[N] | dinv f32[N] | histg u32[SCAN_LEN] | part u32[1024] |
    //     tmp u64[E] | h f32[16N] | t f32[N]   (~67.3 MB)
    unsigned* cnt   = (unsigned*)d_ws;
    float*    dinv  = (float*)(cnt + N_NODES);
    unsigned* histg = (unsigned*)(dinv + N_NODES);
    unsigned* part  = histg + SCAN_LEN;
    unsigned long long* tmp = (unsigned long long*)(part + 1024);
    float*    h     = (float*)(tmp + N_EDGES);
    float*    t     = h + (size_t)N_NODES * HIDDEN;

    const int B = 256;
    const int gN = (N_NODES + B - 1) / B;
    const int gE = (N_EDGES + B - 1) / B;

    hipMemsetAsync(cnt, 0, N_NODES * sizeof(unsigned), stream);
    k_count_hist<<<GA, B, 0, stream>>>(col, cnt, histg);
    k_dinv<<<gN, B, 0, stream>>>(cnt, dinv);
    k_scan1<<<NB_SCAN, SCAN_B, 0, stream>>>(histg, part);
    k_scan2<<<1, SCAN_B, 0, stream>>>(part);
    k_scan3<<<(SCAN_LEN + B - 1) / B, B, 0, stream>>>(histg, part);
    kA_scat<<<GA, B, 0, stream>>>(row, col, histg, tmp);

    k_gemm1<<<(N_NODES + 15) / 16, B, 0, stream>>>(x, W1, h);
    kB1<<<NBUCK, 512, 0, stream>>>(tmp, histg, dinv, h, b1, W2, t);

    k_out_init<<<gN, B, 0, stream>>>(dinv, t, b2, out);
    k_scatter2<<<gE, B, 0, stream>>>(row, col, dinv, t, out);
}

// Round 4
// 1276.629 us; speedup vs baseline: 1.1899x; 1.1899x over previous
//
#include <hip/hip_runtime.h>

#define N_NODES 200000
#define N_EDGES 6400000
#define IN_FEAT 128
#define HIDDEN  16

#define BNODES  128                       // nodes per bucket
#define NBUCK   1563                      // ceil(N_NODES / BNODES)
#define GA      512                       // scatter blocks
#define CHUNK   12500                     // edges per scatter block (GA*CHUNK == N_EDGES)

// ---------------- fused degree count + bucket histogram ----------------

__global__ __launch_bounds__(256) void k_count_hist(const int* __restrict__ col,
                                                    unsigned* __restrict__ cnt,
                                                    unsigned* __restrict__ bucketTot) {
    __shared__ unsigned bh[NBUCK];
    for (int i = threadIdx.x; i < NBUCK; i += 256) bh[i] = 0u;
    __syncthreads();
    const int base = blockIdx.x * CHUNK;
    for (int idx = threadIdx.x; idx < CHUNK; idx += 256) {
        int c = col[base + idx];
        atomicAdd(&cnt[c], 1u);
        atomicAdd(&bh[c >> 7], 1u);
    }
    __syncthreads();
    for (int b = threadIdx.x; b < NBUCK; b += 256)
        if (bh[b]) atomicAdd(&bucketTot[b], bh[b]);
}

__global__ void k_dinv(const unsigned* __restrict__ cnt, float* __restrict__ dinv) {
    int i = blockIdx.x * blockDim.x + threadIdx.x;
    if (i < N_NODES) dinv[i] = rsqrtf((float)cnt[i] + 1.0f);   // +1 self-loop
}

// ---------------- single-block exclusive scan of bucketTot (1563 values) ----------------

__global__ __launch_bounds__(512) void k_scan(const unsigned* __restrict__ bucketTot,
                                              unsigned* __restrict__ base,
                                              unsigned* __restrict__ gcur) {
    __shared__ unsigned s[512];
    __shared__ unsigned carry;
    if (threadIdx.x == 0) carry = 0u;
    __syncthreads();
    for (int c0 = 0; c0 < NBUCK; c0 += 512) {
        int i = c0 + threadIdx.x;
        unsigned v = (i < NBUCK) ? bucketTot[i] : 0u;
        s[threadIdx.x] = v;
        __syncthreads();
        for (int d = 1; d < 512; d <<= 1) {
            unsigned u = (threadIdx.x >= d) ? s[threadIdx.x - d] : 0u;
            __syncthreads();
            s[threadIdx.x] += u;
            __syncthreads();
        }
        if (i < NBUCK) {
            unsigned e = s[threadIdx.x] - v + carry;
            base[i] = e;
            gcur[i * 16] = e;        // padded cursor: 1 per 64B line
        }
        __syncthreads();
        if (threadIdx.x == 0) carry += s[511];
        __syncthreads();
    }
    if (threadIdx.x == 0) base[NBUCK] = N_EDGES;
}

// ---------------- bucket scatter: 3-phase range claiming ----------------
// Phase 1: LDS per-bucket count. Phase 2: one global atomic per (block,bucket)
// claims a contiguous range. Phase 3: re-read (L2-hot) and scatter via LDS
// cursors — each block's writes per bucket land in ~1 private cache line.

__global__ __launch_bounds__(512) void kA_scat(const int* __restrict__ row,
                                               const int* __restrict__ col,
                                               unsigned* __restrict__ gcur,
                                               unsigned long long* __restrict__ tmp) {
    __shared__ unsigned cntL[NBUCK];
    __shared__ unsigned curL[NBUCK];
    const int tid = threadIdx.x;
    const int base0 = blockIdx.x * CHUNK;
    for (int b = tid; b < NBUCK; b += 512) cntL[b] = 0u;
    __syncthreads();
    for (int idx = tid; idx < CHUNK; idx += 512) {
        int c = col[base0 + idx];
        atomicAdd(&cntL[c >> 7], 1u);
    }
    __syncthreads();
    for (int b = tid; b < NBUCK; b += 512) {
        unsigned n = cntL[b];
        curL[b] = n ? atomicAdd(&gcur[b * 16], n) : 0u;
    }
    __syncthreads();
    for (int idx = tid; idx < CHUNK; idx += 512) {
        int e = base0 + idx;
        unsigned c = (unsigned)col[e];           // L2-hot re-read
        unsigned s = (unsigned)row[e];
        unsigned slot = atomicAdd(&curL[c >> 7], 1u);
        tmp[slot] = ((unsigned long long)c << 32) | s;
    }
}

// ---------------- layer-1 GEMM: h = x @ W1 ----------------

__global__ __launch_bounds__(256) void k_gemm1(const float* __restrict__ x,
                                               const float* __restrict__ W1,
                                               float* __restrict__ h) {
    __shared__ float xs[16][132];
    __shared__ float ws[IN_FEAT * HIDDEN];
    const int tid = threadIdx.x;
    const int block_node = blockIdx.x * 16;
    for (int i = tid; i < IN_FEAT * HIDDEN; i += 256) ws[i] = W1[i];
    const int rows = min(16, N_NODES - block_node);
    const float4* x4 = (const float4*)(x + (size_t)block_node * IN_FEAT);
    for (int i = tid; i < rows * 32; i += 256) {
        float4 v = x4[i];
        int r = i >> 5, c = (i & 31) << 2;
        *(float4*)&xs[r][c] = v;
    }
    __syncthreads();
    const int n = tid >> 4, f = tid & 15;
    if (block_node + n < N_NODES) {
        float acc = 0.f;
        #pragma unroll 8
        for (int k = 0; k < IN_FEAT; ++k)
            acc = fmaf(xs[n][k], ws[k * HIDDEN + f], acc);
        h[(size_t)(block_node + n) * HIDDEN + f] = acc;
    }
}

// ---------------- layer-1 aggregate (one block per 128-node bucket) ----------------
// Fused: LDS aggregation + self-loop + bias + relu + W2 reduction -> t.

__global__ __launch_bounds__(512) void kB1(const unsigned long long* __restrict__ tmp,
                                           const unsigned* __restrict__ base,
                                           const float* __restrict__ dinv,
                                           const float* __restrict__ h,
                                           const float* __restrict__ b1,
                                           const float* __restrict__ W2,
                                           float* __restrict__ t) {
    __shared__ float aggL[BNODES * 17];
    const int tid = threadIdx.x;
    const int b = blockIdx.x;
    const int baseNode = b * BNODES;
    for (int i = tid; i < BNODES * 17; i += 512) aggL[i] = 0.f;
    const unsigned start = base[b], end = base[b + 1];
    const int g = tid >> 4, f = tid & 15;
    const float b1f = b1[f], w2f = W2[f];
    __syncthreads();
    unsigned k = start + g;
    for (; k + 32 < end; k += 64) {                  // unroll 2: two gathers in flight
        unsigned long long p0 = tmp[k], p1 = tmp[k + 32];
        unsigned s0 = (unsigned)p0, s1 = (unsigned)p1;
        unsigned d0 = ((unsigned)(p0 >> 32)) & (BNODES - 1);
        unsigned d1 = ((unsigned)(p1 >> 32)) & (BNODES - 1);
        float w0 = dinv[s0], w1 = dinv[s1];
        float h0 = h[(size_t)s0 * HIDDEN + f];
        float h1 = h[(size_t)s1 * HIDDEN + f];
        unsafeAtomicAdd(&aggL[d0 * 17 + f], w0 * h0);
        unsafeAtomicAdd(&aggL[d1 * 17 + f], w1 * h1);
    }
    if (k < end) {
        unsigned long long p0 = tmp[k];
        unsigned s0 = (unsigned)p0;
        unsigned d0 = ((unsigned)(p0 >> 32)) & (BNODES - 1);
        unsafeAtomicAdd(&aggL[d0 * 17 + f], dinv[s0] * h[(size_t)s0 * HIDDEN + f]);
    }
    __syncthreads();
    for (int n = g; n < BNODES; n += 32) {
        int node = baseNode + n;
        if (node < N_NODES) {
            float di = dinv[node];
            float pre = di * (aggL[n * 17 + f] + di * h[(size_t)node * HIDDEN + f]);
            float r = fmaxf(pre + b1f, 0.f) * w2f;
            r += __shfl_xor(r, 8, 16);
            r += __shfl_xor(r, 4, 16);
            r += __shfl_xor(r, 2, 16);
            r += __shfl_xor(r, 1, 16);
            if (f == 0) t[node] = r;
        }
    }
}

// ---------------- layer 2: bucket aggregate from sorted tmp (deterministic) ----------------

__global__ __launch_bounds__(256) void kB2(const unsigned long long* __restrict__ tmp,
                                           const unsigned* __restrict__ base,
                                           const float* __restrict__ dinv,
                                           const float* __restrict__ t,
                                           const float* __restrict__ b2,
                                           float* __restrict__ out) {
    __shared__ float a2[BNODES];
    const int tid = threadIdx.x;
    const int b = blockIdx.x;
    if (tid < BNODES) a2[tid] = 0.f;
    const unsigned start = base[b], end = base[b + 1];
    __syncthreads();
    for (unsigned k = start + tid; k < end; k += 256) {
        unsigned long long p = tmp[k];
        unsigned s = (unsigned)p;
        unsigned dl = ((unsigned)(p >> 32)) & (BNODES - 1);
        unsafeAtomicAdd(&a2[dl], dinv[s] * t[s]);
    }
    __syncthreads();
    if (tid < BNODES) {
        int node = b * BNODES + tid;
        if (node < N_NODES) {
            float di = dinv[node];
            out[node] = fmaf(di, a2[tid], fmaf(di * di, t[node], b2[0]));
        }
    }
}

// ---------------- launch ----------------

extern "C" void kernel_launch(void* const* d_in, const int* in_sizes, int n_in,
                              void* d_out, int out_size, void* d_ws, size_t ws_size,
                              hipStream_t stream) {
    const float* x   = (const float*)d_in[0];
    const int*   ei  = (const int*)d_in[1];
    const float* W1  = (const float*)d_in[2];
    const float* b1  = (const float*)d_in[3];
    const float* W2  = (const float*)d_in[4];
    const float* b2  = (const float*)d_in[5];
    float* out = (float*)d_out;

    const int* row = ei;               // sources
    const int* col = ei + N_EDGES;     // targets

    // ws: cnt u32[N] | bucketTot u32[NBUCK] | base u32[NBUCK+1] | gcur u32[NBUCK*16]
    //     | dinv f32[N] | tmp u64[E] | h f32[16N] | t f32[N]   (~66.5 MB)
    unsigned* cnt       = (unsigned*)d_ws;
    unsigned* bucketTot = cnt + N_NODES;
    unsigned* base      = bucketTot + NBUCK;
    unsigned* gcur      = base + (NBUCK + 1);
    float*    dinv      = (float*)(gcur + NBUCK * 16);
    unsigned long long* tmp = (unsigned long long*)(dinv + N_NODES);
    float*    h         = (float*)(tmp + N_EDGES);
    float*    t         = h + (size_t)N_NODES * HIDDEN;

    const int B = 256;
    const int gN = (N_NODES + B - 1) / B;

    hipMemsetAsync(cnt, 0, (N_NODES + NBUCK) * sizeof(unsigned), stream);
    k_count_hist<<<GA, B, 0, stream>>>(col, cnt, bucketTot);
    k_dinv<<<gN, B, 0, stream>>>(cnt, dinv);
    k_scan<<<1, 512, 0, stream>>>(bucketTot, base, gcur);
    kA_scat<<<GA, 512, 0, stream>>>(row, col, gcur, tmp);

    k_gemm1<<<(N_NODES + 15) / 16, B, 0, stream>>>(x, W1, h);
    kB1<<<NBUCK, 512, 0, stream>>>(tmp, base, dinv, h, b1, W2, t);
    kB2<<<NBUCK, 256, 0, stream>>>(tmp, base, dinv, t, b2, out);
}

// Round 6
// 1246.818 us; speedup vs baseline: 1.2183x; 1.0239x over previous
//
#include <hip/hip_runtime.h>
#include <hip/hip_fp16.h>

#define N_NODES 200000
#define N_EDGES 6400000
#define IN_FEAT 128
#define HIDDEN  16

#define BNODES  128                       // nodes per bucket
#define NBUCK   1563                      // ceil(N_NODES / BNODES)
#define GA      512                       // scatter blocks
#define CHUNK   12500                     // edges per scatter block (GA*CHUNK == N_EDGES)

#define SRC_BITS 18
#define SRC_MASK ((1u << SRC_BITS) - 1u)

typedef float v4f __attribute__((ext_vector_type(4)));

// ---------------- fused degree count + bucket histogram ----------------

__global__ __launch_bounds__(256) void k_count_hist(const int* __restrict__ col,
                                                    unsigned* __restrict__ cnt,
                                                    unsigned* __restrict__ bucketTot) {
    __shared__ unsigned bh[NBUCK];
    for (int i = threadIdx.x; i < NBUCK; i += 256) bh[i] = 0u;
    __syncthreads();
    const int base = blockIdx.x * CHUNK;
    for (int idx = threadIdx.x; idx < CHUNK; idx += 256) {
        int c = col[base + idx];
        atomicAdd(&cnt[c], 1u);
        atomicAdd(&bh[c >> 7], 1u);
    }
    __syncthreads();
    for (int b = threadIdx.x; b < NBUCK; b += 256)
        if (bh[b]) atomicAdd(&bucketTot[b], bh[b]);
}

__global__ void k_dinv(const unsigned* __restrict__ cnt, float* __restrict__ dinv) {
    int i = blockIdx.x * blockDim.x + threadIdx.x;
    if (i < N_NODES) dinv[i] = rsqrtf((float)cnt[i] + 1.0f);   // +1 self-loop
}

// ---------------- single-block exclusive scan of bucketTot (1563 values) ----------------

__global__ __launch_bounds__(512) void k_scan(const unsigned* __restrict__ bucketTot,
                                              unsigned* __restrict__ base,
                                              unsigned* __restrict__ gcur) {
    __shared__ unsigned s[512];
    __shared__ unsigned carry;
    if (threadIdx.x == 0) carry = 0u;
    __syncthreads();
    for (int c0 = 0; c0 < NBUCK; c0 += 512) {
        int i = c0 + threadIdx.x;
        unsigned v = (i < NBUCK) ? bucketTot[i] : 0u;
        s[threadIdx.x] = v;
        __syncthreads();
        for (int d = 1; d < 512; d <<= 1) {
            unsigned u = (threadIdx.x >= d) ? s[threadIdx.x - d] : 0u;
            __syncthreads();
            s[threadIdx.x] += u;
            __syncthreads();
        }
        if (i < NBUCK) {
            unsigned e = s[threadIdx.x] - v + carry;
            base[i] = e;
            gcur[i * 16] = e;        // padded cursor: 1 per 64B line
        }
        __syncthreads();
        if (threadIdx.x == 0) carry += s[511];
        __syncthreads();
    }
    if (threadIdx.x == 0) base[NBUCK] = N_EDGES;
}

// ---------------- bucket scatter: 3-phase range claiming, u32 packed ----------------

__global__ __launch_bounds__(512) void kA_scat(const int* __restrict__ row,
                                               const int* __restrict__ col,
                                               unsigned* __restrict__ gcur,
                                               unsigned* __restrict__ tmp) {
    __shared__ unsigned cntL[NBUCK];
    __shared__ unsigned curL[NBUCK];
    const int tid = threadIdx.x;
    const int base0 = blockIdx.x * CHUNK;
    for (int b = tid; b < NBUCK; b += 512) cntL[b] = 0u;
    __syncthreads();
    for (int idx = tid; idx < CHUNK; idx += 512) {
        int c = col[base0 + idx];
        atomicAdd(&cntL[c >> 7], 1u);
    }
    __syncthreads();
    for (int b = tid; b < NBUCK; b += 512) {
        unsigned n = cntL[b];
        curL[b] = n ? atomicAdd(&gcur[b * 16], n) : 0u;
    }
    __syncthreads();
    for (int idx = tid; idx < CHUNK; idx += 512) {
        int e = base0 + idx;
        unsigned c = (unsigned)col[e];                       // L2-hot re-read
        unsigned s = (unsigned)__builtin_nontemporal_load(&row[e]);
        unsigned slot = atomicAdd(&curL[c >> 7], 1u);
        tmp[slot] = ((c & (BNODES - 1u)) << SRC_BITS) | s;   // dl<<18 | src
    }
}

// ---------------- layer-1 GEMM: h' = dinv .* (x @ W1), fp16 ----------------

__global__ __launch_bounds__(256) void k_gemm1(const float* __restrict__ x,
                                               const float* __restrict__ W1,
                                               const float* __restrict__ dinv,
                                               __half* __restrict__ h16) {
    __shared__ float xs[16][132];
    __shared__ float ws[IN_FEAT * HIDDEN];
    const int tid = threadIdx.x;
    const int block_node = blockIdx.x * 16;
    for (int i = tid; i < IN_FEAT * HIDDEN; i += 256) ws[i] = W1[i];
    const int rows = min(16, N_NODES - block_node);
    const v4f* x4 = (const v4f*)(x + (size_t)block_node * IN_FEAT);
    for (int i = tid; i < rows * 32; i += 256) {
        v4f v = __builtin_nontemporal_load(&x4[i]);
        int r = i >> 5, c = (i & 31) << 2;
        *(v4f*)&xs[r][c] = v;
    }
    __syncthreads();
    const int n = tid >> 4, f = tid & 15;
    const int node = block_node + n;
    if (node < N_NODES) {
        float acc = 0.f;
        #pragma unroll 8
        for (int k = 0; k < IN_FEAT; ++k)
            acc = fmaf(xs[n][k], ws[k * HIDDEN + f], acc);
        h16[(size_t)node * HIDDEN + f] = __float2half(dinv[node] * acc);
    }
}

// ---------------- layer-1 aggregate (one block per 128-node bucket) ----------------
// Per edge: 1 broadcast packed read (nt) + 1 fp16 gather (2B/lane, 32B/edge)
// + 1 LDS atomic. Epilogue fuses self-loop + bias + relu + W2 + dinv -> t'.

__global__ __launch_bounds__(512) void kB1(const unsigned* __restrict__ tmp,
                                           const unsigned* __restrict__ base,
                                           const float* __restrict__ dinv,
                                           const __half* __restrict__ h16,
                                           const float* __restrict__ b1,
                                           const float* __restrict__ W2,
                                           float* __restrict__ t) {
    __shared__ float aggL[BNODES * 17];
    const int tid = threadIdx.x;
    const int b = blockIdx.x;
    const int baseNode = b * BNODES;
    for (int i = tid; i < BNODES * 17; i += 512) aggL[i] = 0.f;
    const unsigned start = base[b], end = base[b + 1];
    const int g = tid >> 4, f = tid & 15;
    const float b1f = b1[f], w2f = W2[f];
    __syncthreads();
    unsigned k = start + 4 * g;
    for (; k + 3 < end; k += 128) {                  // 4 edges per group-iter
        unsigned p0 = __builtin_nontemporal_load(&tmp[k]);
        unsigned p1 = __builtin_nontemporal_load(&tmp[k + 1]);
        unsigned p2 = __builtin_nontemporal_load(&tmp[k + 2]);
        unsigned p3 = __builtin_nontemporal_load(&tmp[k + 3]);
        float h0 = __half2float(h16[(size_t)(p0 & SRC_MASK) * HIDDEN + f]);
        float h1 = __half2float(h16[(size_t)(p1 & SRC_MASK) * HIDDEN + f]);
        float h2 = __half2float(h16[(size_t)(p2 & SRC_MASK) * HIDDEN + f]);
        float h3 = __half2float(h16[(size_t)(p3 & SRC_MASK) * HIDDEN + f]);
        unsafeAtomicAdd(&aggL[(p0 >> SRC_BITS) * 17 + f], h0);
        unsafeAtomicAdd(&aggL[(p1 >> SRC_BITS) * 17 + f], h1);
        unsafeAtomicAdd(&aggL[(p2 >> SRC_BITS) * 17 + f], h2);
        unsafeAtomicAdd(&aggL[(p3 >> SRC_BITS) * 17 + f], h3);
    }
    for (int q = 0; q < 3 && k < end; ++q, ++k) {    // tail (this group's window)
        unsigned p = __builtin_nontemporal_load(&tmp[k]);
        float hv = __half2float(h16[(size_t)(p & SRC_MASK) * HIDDEN + f]);
        unsafeAtomicAdd(&aggL[(p >> SRC_BITS) * 17 + f], hv);
    }
    __syncthreads();
    for (int n = g; n < BNODES; n += 32) {
        int node = baseNode + n;
        if (node < N_NODES) {
            float di = dinv[node];
            float selfh = __half2float(h16[(size_t)node * HIDDEN + f]);  // = dinv*h
            float pre = di * (aggL[n * 17 + f] + selfh);
            float r = fmaxf(pre + b1f, 0.f) * w2f;
            r += __shfl_xor(r, 8, 16);
            r += __shfl_xor(r, 4, 16);
            r += __shfl_xor(r, 2, 16);
            r += __shfl_xor(r, 1, 16);
            if (f == 0) t[node] = di * r;            // t' = dinv * t
        }
    }
}

// ---------------- layer 2: bucket aggregate of t' ----------------

__global__ __launch_bounds__(256) void kB2(const unsigned* __restrict__ tmp,
                                           const unsigned* __restrict__ base,
                                           const float* __restrict__ dinv,
                                           const float* __restrict__ t,
                                           const float* __restrict__ b2,
                                           float* __restrict__ out) {
    __shared__ float a2[BNODES];
    const int tid = threadIdx.x;
    const int b = blockIdx.x;
    if (tid < BNODES) a2[tid] = 0.f;
    const unsigned start = base[b], end = base[b + 1];
    const float b2f = b2[0];
    __syncthreads();
    for (unsigned k = start + tid; k < end; k += 256) {
        unsigned p = __builtin_nontemporal_load(&tmp[k]);
        unsafeAtomicAdd(&a2[p >> SRC_BITS], t[p & SRC_MASK]);   // t' gather, L2-hot
    }
    __syncthreads();
    if (tid < BNODES) {
        int node = b * BNODES + tid;
        if (node < N_NODES) {
            float di = dinv[node];
            out[node] = fmaf(di, a2[tid] + t[node], b2f);   // di*(sum t' + t'_self)+b2
        }
    }
}

// ---------------- launch ----------------

extern "C" void kernel_launch(void* const* d_in, const int* in_sizes, int n_in,
                              void* d_out, int out_size, void* d_ws, size_t ws_size,
                              hipStream_t stream) {
    const float* x   = (const float*)d_in[0];
    const int*   ei  = (const int*)d_in[1];
    const float* W1  = (const float*)d_in[2];
    const float* b1  = (const float*)d_in[3];
    const float* W2  = (const float*)d_in[4];
    const float* b2  = (const float*)d_in[5];
    float* out = (float*)d_out;

    const int* row = ei;               // sources
    const int* col = ei + N_EDGES;     // targets

    // ws: cnt u32[N] | bucketTot u32[NBUCK] | base u32[NBUCK+1] | gcur u32[NBUCK*16]
    //     | dinv f32[N] | tmp u32[E] | h16 fp16[16N] | t f32[N]   (~35 MB)
    unsigned* cnt       = (unsigned*)d_ws;
    unsigned* bucketTot = cnt + N_NODES;
    unsigned* base      = bucketTot + NBUCK;
    unsigned* gcur      = base + (NBUCK + 1);
    float*    dinv      = (float*)(gcur + NBUCK * 16);
    unsigned* tmp       = (unsigned*)(dinv + N_NODES);
    __half*   h16       = (__half*)(tmp + N_EDGES);
    float*    t         = (float*)(h16 + (size_t)N_NODES * HIDDEN);

    const int B = 256;
    const int gN = (N_NODES + B - 1) / B;

    (void)hipMemsetAsync(cnt, 0, (N_NODES + NBUCK) * sizeof(unsigned), stream);
    k_count_hist<<<GA, B, 0, stream>>>(col, cnt, bucketTot);
    k_dinv<<<gN, B, 0, stream>>>(cnt, dinv);
    k_scan<<<1, 512, 0, stream>>>(bucketTot, base, gcur);
    kA_scat<<<GA, 512, 0, stream>>>(row, col, gcur, tmp);

    k_gemm1<<<(N_NODES + 15) / 16, B, 0, stream>>>(x, W1, dinv, h16);
    kB1<<<NBUCK, 512, 0, stream>>>(tmp, base, dinv, h16, b1, W2, t);
    kB2<<<NBUCK, 256, 0, stream>>>(tmp, base, dinv, t, b2, out);
}

// Round 7
// 1105.659 us; speedup vs baseline: 1.3739x; 1.1277x over previous
//
#include <hip/hip_runtime.h>
#include <hip/hip_fp16.h>

#define N_NODES 200000
#define N_EDGES 6400000
#define IN_FEAT 128
#define HIDDEN  16

typedef float v4f __attribute__((ext_vector_type(4)));

// ---------------- degree count ----------------

__global__ void k_count(const int* __restrict__ col, unsigned* __restrict__ cnt) {
    int e = blockIdx.x * blockDim.x + threadIdx.x;
    if (e < N_EDGES) atomicAdd(&cnt[col[e]], 1u);
}

__global__ void k_dinv(const unsigned* __restrict__ cnt, float* __restrict__ dinv) {
    int i = blockIdx.x * blockDim.x + threadIdx.x;
    if (i < N_NODES) dinv[i] = rsqrtf((float)cnt[i] + 1.0f);   // +1 self-loop
}

// ---------------- layer-1 GEMM: h16 = dinv .* (x @ W1), fp16 (dinv_src folded) ----------------

__global__ __launch_bounds__(256) void k_gemm1(const float* __restrict__ x,
                                               const float* __restrict__ W1,
                                               const float* __restrict__ dinv,
                                               __half* __restrict__ h16) {
    __shared__ float xs[16][132];
    __shared__ float ws[IN_FEAT * HIDDEN];
    const int tid = threadIdx.x;
    const int block_node = blockIdx.x * 16;
    for (int i = tid; i < IN_FEAT * HIDDEN; i += 256) ws[i] = W1[i];
    const int rows = min(16, N_NODES - block_node);
    const v4f* x4 = (const v4f*)(x + (size_t)block_node * IN_FEAT);
    for (int i = tid; i < rows * 32; i += 256) {
        v4f v = __builtin_nontemporal_load(&x4[i]);
        int r = i >> 5, c = (i & 31) << 2;
        *(v4f*)&xs[r][c] = v;
    }
    __syncthreads();
    const int n = tid >> 4, f = tid & 15;
    const int node = block_node + n;
    if (node < N_NODES) {
        float acc = 0.f;
        #pragma unroll 8
        for (int k = 0; k < IN_FEAT; ++k)
            acc = fmaf(xs[n][k], ws[k * HIDDEN + f], acc);
        h16[(size_t)node * HIDDEN + f] = __float2half(dinv[node] * acc);
    }
}

// ---------------- layer-1 flat edge scatter (R1 shape, halved gather bytes) ----------------
// 16 lanes per edge: h16[src] gather is 32B contiguous; atomics hit one 64B line.
// No per-edge dinv reads: dinv_src is folded into h16, dinv_dst applied in k_node2.

__global__ __launch_bounds__(256) void k_scat1(const int* __restrict__ row,
                                               const int* __restrict__ col,
                                               const __half* __restrict__ h16,
                                               float* __restrict__ agg) {
    long long tid = (long long)blockIdx.x * 256 + threadIdx.x;
    long long e = tid >> 4;
    int f = (int)(tid & 15);
    if (e >= N_EDGES) return;
    int r = row[e], c = col[e];
    float v = __half2float(h16[(size_t)r * HIDDEN + f]);
    unsafeAtomicAdd(&agg[(size_t)c * HIDDEN + f], v);
}

// ---------------- fused self-loop + bias + relu + W2 + dinv -> t' ----------------
// t'[i] = dinv_i * sum_f relu(dinv_i*(agg_f + h16_f) + b1_f) * W2_f

__global__ __launch_bounds__(256) void k_node2(const float* __restrict__ agg,
                                               const __half* __restrict__ h16,
                                               const float* __restrict__ dinv,
                                               const float* __restrict__ b1,
                                               const float* __restrict__ W2,
                                               float* __restrict__ tp) {
    int tid = blockIdx.x * blockDim.x + threadIdx.x;
    int i = tid >> 4, f = tid & 15;
    if (i >= N_NODES) return;
    float di = dinv[i];
    float pre = di * (agg[(size_t)i * HIDDEN + f]
                      + __half2float(h16[(size_t)i * HIDDEN + f]));
    float r = fmaxf(pre + b1[f], 0.f) * W2[f];
    r += __shfl_xor(r, 8, 16);
    r += __shfl_xor(r, 4, 16);
    r += __shfl_xor(r, 2, 16);
    r += __shfl_xor(r, 1, 16);
    if (f == 0) tp[i] = di * r;          // t' = dinv * t
}

// ---------------- layer-2 flat scatter: agg2[c] += t'[r] ----------------

__global__ __launch_bounds__(256) void k_scat2(const int* __restrict__ row,
                                               const int* __restrict__ col,
                                               const float* __restrict__ tp,
                                               float* __restrict__ agg2) {
    int e = blockIdx.x * blockDim.x + threadIdx.x;
    if (e < N_EDGES) unsafeAtomicAdd(&agg2[col[e]], tp[row[e]]);
}

// ---------------- finalize: out = b2 + dinv*(t'_self + agg2) ----------------

__global__ void k_fin(const float* __restrict__ tp, const float* __restrict__ agg2,
                      const float* __restrict__ dinv, const float* __restrict__ b2,
                      float* __restrict__ out) {
    int i = blockIdx.x * blockDim.x + threadIdx.x;
    if (i < N_NODES) out[i] = fmaf(dinv[i], tp[i] + agg2[i], b2[0]);
}

// ---------------- launch ----------------

extern "C" void kernel_launch(void* const* d_in, const int* in_sizes, int n_in,
                              void* d_out, int out_size, void* d_ws, size_t ws_size,
                              hipStream_t stream) {
    const float* x   = (const float*)d_in[0];
    const int*   ei  = (const int*)d_in[1];
    const float* W1  = (const float*)d_in[2];
    const float* b1  = (const float*)d_in[3];
    const float* W2  = (const float*)d_in[4];
    const float* b2  = (const float*)d_in[5];
    float* out = (float*)d_out;

    const int* row = ei;               // sources
    const int* col = ei + N_EDGES;     // targets

    // ws (floats): [cnt u32 N][agg f32 16N][agg2 f32 N] (zeroed together)
    //              [dinv N][tp N][h16 fp16 16N = 8N floats]   total 28N = 22.4 MB
    unsigned* cnt  = (unsigned*)d_ws;
    float*    agg  = (float*)(cnt + N_NODES);
    float*    agg2 = agg + (size_t)N_NODES * HIDDEN;
    float*    dinv = agg2 + N_NODES;
    float*    tp   = dinv + N_NODES;
    __half*   h16  = (__half*)(tp + N_NODES);

    const int B = 256;
    const int gN   = (N_NODES + B - 1) / B;
    const int gE   = (N_EDGES + B - 1) / B;
    const int gE16 = (int)(((long long)N_EDGES * 16 + B - 1) / B);
    const int gN16 = (N_NODES * 16 + B - 1) / B;

    (void)hipMemsetAsync(cnt, 0, (size_t)(N_NODES * 18) * sizeof(unsigned), stream);
    k_count<<<gE, B, 0, stream>>>(col, cnt);
    k_dinv<<<gN, B, 0, stream>>>(cnt, dinv);

    k_gemm1<<<(N_NODES + 15) / 16, B, 0, stream>>>(x, W1, dinv, h16);
    k_scat1<<<gE16, B, 0, stream>>>(row, col, h16, agg);
    k_node2<<<gN16, B, 0, stream>>>(agg, h16, dinv, b1, W2, tp);
    k_scat2<<<gE, B, 0, stream>>>(row, col, tp, agg2);
    k_fin<<<gN, B, 0, stream>>>(tp, agg2, dinv, b2, out);
}

// Round 8
// 1057.736 us; speedup vs baseline: 1.4361x; 1.0453x over previous
//
#include <hip/hip_runtime.h>
#include <hip/hip_fp16.h>

#define N_NODES 200000
#define N_EDGES 6400000
#define IN_FEAT 128
#define HIDDEN  16

typedef float v4f __attribute__((ext_vector_type(4)));
typedef _Float16 f16x8 __attribute__((ext_vector_type(8)));
typedef float f32x4 __attribute__((ext_vector_type(4)));

// ---------------- degree count ----------------

__global__ void k_count(const int* __restrict__ col, unsigned* __restrict__ cnt) {
    int e = blockIdx.x * blockDim.x + threadIdx.x;
    if (e < N_EDGES) atomicAdd(&cnt[col[e]], 1u);
}

__global__ void k_dinv(const unsigned* __restrict__ cnt, float* __restrict__ dinv) {
    int i = blockIdx.x * blockDim.x + threadIdx.x;
    if (i < N_NODES) dinv[i] = rsqrtf((float)cnt[i] + 1.0f);   // +1 self-loop
}

// ---------------- layer-1 GEMM via MFMA: h16 = dinv .* (x @ W1), fp16 ----------------
// One wave per 16-node tile. A = x-tile (f32->f16 in flight), B = W1 (f16 frags,
// loaded once per wave), 4 x mfma_f32_16x16x32_f16 over K=128. N_NODES = 12500*16.

__global__ __launch_bounds__(256) void k_gemm1(const float* __restrict__ x,
                                               const float* __restrict__ W1,
                                               const float* __restrict__ dinv,
                                               __half* __restrict__ h16) {
    const int wave = (blockIdx.x * 256 + threadIdx.x) >> 6;   // tile id
    const int lane = threadIdx.x & 63;
    const int m16 = lane & 15;        // A: node-within-tile | B/D: feature
    const int quad = lane >> 4;
    if (wave * 16 >= N_NODES) return;

    // B fragments: B[k][n], n = lane&15, k = quad*8+j  (W1 row-major [128][16])
    f16x8 bf[4];
    #pragma unroll
    for (int kb = 0; kb < 4; ++kb)
        #pragma unroll
        for (int j = 0; j < 8; ++j)
            bf[kb][j] = (_Float16)W1[(kb * 32 + quad * 8 + j) * HIDDEN + m16];

    const int node0 = wave * 16;
    const float* xrow = x + (size_t)(node0 + m16) * IN_FEAT + quad * 8;
    f32x4 acc = {0.f, 0.f, 0.f, 0.f};
    #pragma unroll
    for (int kb = 0; kb < 4; ++kb) {
        const v4f* p = (const v4f*)(xrow + kb * 32);
        v4f u0 = p[0], u1 = p[1];
        f16x8 af;
        af[0] = (_Float16)u0.x; af[1] = (_Float16)u0.y;
        af[2] = (_Float16)u0.z; af[3] = (_Float16)u0.w;
        af[4] = (_Float16)u1.x; af[5] = (_Float16)u1.y;
        af[6] = (_Float16)u1.z; af[7] = (_Float16)u1.w;
        acc = __builtin_amdgcn_mfma_f32_16x16x32_f16(af, bf[kb], acc, 0, 0, 0);
    }
    // D: row m = quad*4 + r, col = m16
    #pragma unroll
    for (int r = 0; r < 4; ++r) {
        int node = node0 + quad * 4 + r;
        h16[(size_t)node * HIDDEN + m16] = __float2half(dinv[node] * acc[r]);
    }
}

// ---------------- layer-1 flat edge scatter, packed-f16 atomics ----------------
// 8 lanes per edge: lane l handles features 2l,2l+1 as one __half2.
// 51.2M pk atomics instead of 102.4M f32 atomics.

__global__ __launch_bounds__(256) void k_scat1(const int* __restrict__ row,
                                               const int* __restrict__ col,
                                               const unsigned* __restrict__ h16u,
                                               __half2* __restrict__ agg) {
    long long tid = (long long)blockIdx.x * 256 + threadIdx.x;
    long long e = tid >> 3;
    int l = (int)(tid & 7);
    if (e >= N_EDGES) return;
    int r = row[e], c = col[e];
    unsigned v = h16u[(size_t)r * 8 + l];
    unsafeAtomicAdd(&agg[(size_t)c * 8 + l], *(const __half2*)&v);
}

// ---------------- fused self-loop + bias + relu + W2 + dinv -> t' ----------------

__global__ __launch_bounds__(256) void k_node2(const __half* __restrict__ aggh,
                                               const __half* __restrict__ h16,
                                               const float* __restrict__ dinv,
                                               const float* __restrict__ b1,
                                               const float* __restrict__ W2,
                                               float* __restrict__ tp) {
    int tid = blockIdx.x * blockDim.x + threadIdx.x;
    int i = tid >> 4, f = tid & 15;
    if (i >= N_NODES) return;
    float di = dinv[i];
    float pre = di * (__half2float(aggh[(size_t)i * HIDDEN + f])
                      + __half2float(h16[(size_t)i * HIDDEN + f]));
    float r = fmaxf(pre + b1[f], 0.f) * W2[f];
    r += __shfl_xor(r, 8, 16);
    r += __shfl_xor(r, 4, 16);
    r += __shfl_xor(r, 2, 16);
    r += __shfl_xor(r, 1, 16);
    if (f == 0) tp[i] = di * r;          // t' = dinv * t
}

// ---------------- layer-2 flat scatter: agg2[c] += t'[r] ----------------

__global__ __launch_bounds__(256) void k_scat2(const int* __restrict__ row,
                                               const int* __restrict__ col,
                                               const float* __restrict__ tp,
                                               float* __restrict__ agg2) {
    int e = blockIdx.x * blockDim.x + threadIdx.x;
    if (e < N_EDGES) unsafeAtomicAdd(&agg2[col[e]], tp[row[e]]);
}

// ---------------- finalize: out = b2 + dinv*(t'_self + agg2) ----------------

__global__ void k_fin(const float* __restrict__ tp, const float* __restrict__ agg2,
                      const float* __restrict__ dinv, const float* __restrict__ b2,
                      float* __restrict__ out) {
    int i = blockIdx.x * blockDim.x + threadIdx.x;
    if (i < N_NODES) out[i] = fmaf(dinv[i], tp[i] + agg2[i], b2[0]);
}

// ---------------- launch ----------------

extern "C" void kernel_launch(void* const* d_in, const int* in_sizes, int n_in,
                              void* d_out, int out_size, void* d_ws, size_t ws_size,
                              hipStream_t stream) {
    const float* x   = (const float*)d_in[0];
    const int*   ei  = (const int*)d_in[1];
    const float* W1  = (const float*)d_in[2];
    const float* b1  = (const float*)d_in[3];
    const float* W2  = (const float*)d_in[4];
    const float* b2  = (const float*)d_in[5];
    float* out = (float*)d_out;

    const int* row = ei;               // sources
    const int* col = ei + N_EDGES;     // targets

    // ws zeroed prefix: [cnt u32 N][agg2 f32 N][agg fp16 16N = 8N u32]  (10N u32 = 8 MB)
    // then: [dinv f32 N][tp f32 N][h16 fp16 16N]
    unsigned* cnt  = (unsigned*)d_ws;
    float*    agg2 = (float*)(cnt + N_NODES);
    __half2*  agg  = (__half2*)(agg2 + N_NODES);           // 8 half2 per node
    float*    dinv = (float*)((unsigned*)agg + (size_t)N_NODES * 8);
    float*    tp   = dinv + N_NODES;
    __half*   h16  = (__half*)(tp + N_NODES);

    const int B = 256;
    const int gN   = (N_NODES + B - 1) / B;
    const int gE   = (N_EDGES + B - 1) / B;
    const int gE8  = (int)(((long long)N_EDGES * 8 + B - 1) / B);
    const int gN16 = (N_NODES * 16 + B - 1) / B;

    (void)hipMemsetAsync(cnt, 0, (size_t)N_NODES * 10 * sizeof(unsigned), stream);
    k_count<<<gE, B, 0, stream>>>(col, cnt);
    k_dinv<<<gN, B, 0, stream>>>(cnt, dinv);

    k_gemm1<<<(N_NODES / 16 + 3) / 4, B, 0, stream>>>(x, W1, dinv, h16);
    k_scat1<<<gE8, B, 0, stream>>>(row, col, (const unsigned*)h16, agg);
    k_node2<<<gN16, B, 0, stream>>>((const __half*)agg, h16, dinv, b1, W2, tp);
    k_scat2<<<gE, B, 0, stream>>>(row, col, tp, agg2);
    k_fin<<<gN, B, 0, stream>>>(tp, agg2, dinv, b2, out);
}

// Round 9
// 843.676 us; speedup vs baseline: 1.8005x; 1.2537x over previous
//
#include <hip/hip_runtime.h>
#include <hip/hip_fp16.h>

#define N_NODES 200000
#define N_EDGES 6400000
#define IN_FEAT 128
#define HIDDEN  16

typedef float v4f __attribute__((ext_vector_type(4)));
typedef _Float16 f16x8 __attribute__((ext_vector_type(8)));
typedef float f32x4 __attribute__((ext_vector_type(4)));

// ======== degree histogram: 7 ranges x 32768 nodes, u16-packed LDS ========
#define CRN 32768
#define CNR 7                 // 7*32768 = 229376 >= N_NODES
#define CB  32                // blocks per range
#define CEPB (N_EDGES / CB)   // 200000 edges per block

__global__ __launch_bounds__(256) void k_hist_cnt(const int* __restrict__ col,
                                                  unsigned* __restrict__ cnt) {
    __shared__ unsigned hs[CRN / 2];          // 64 KB: 2 x u16 counters per entry
    const int range = blockIdx.x >> 5;
    const int chunk = blockIdx.x & 31;
    const unsigned lo = range * CRN;
    for (int i = threadIdx.x; i < CRN / 2; i += 256) hs[i] = 0u;
    __syncthreads();
    const int4* c4 = (const int4*)(col + (size_t)chunk * CEPB);
    const int n4 = CEPB / 4;                  // 50000
    for (int i = threadIdx.x; i < n4; i += 256) {
        int4 v = c4[i];
        unsigned a;
        a = (unsigned)v.x - lo; if (a < CRN) atomicAdd(&hs[a >> 1], 1u << ((a & 1) * 16));
        a = (unsigned)v.y - lo; if (a < CRN) atomicAdd(&hs[a >> 1], 1u << ((a & 1) * 16));
        a = (unsigned)v.z - lo; if (a < CRN) atomicAdd(&hs[a >> 1], 1u << ((a & 1) * 16));
        a = (unsigned)v.w - lo; if (a < CRN) atomicAdd(&hs[a >> 1], 1u << ((a & 1) * 16));
    }
    __syncthreads();
    for (int i = threadIdx.x; i < CRN / 2; i += 256) {   // contiguous merge
        unsigned v = hs[i];
        unsigned node = lo + 2 * i;
        if (node < N_NODES) atomicAdd(&cnt[node], v & 0xffffu);
        if (node + 1 < N_NODES) atomicAdd(&cnt[node + 1], v >> 16);
    }
}

__global__ void k_dinv(const unsigned* __restrict__ cnt, float* __restrict__ dinv) {
    int i = blockIdx.x * blockDim.x + threadIdx.x;
    if (i < N_NODES) dinv[i] = rsqrtf((float)cnt[i] + 1.0f);   // +1 self-loop
}

// ---------------- layer-1 GEMM via MFMA: h16 = dinv .* (x @ W1), fp16 ----------------

__global__ __launch_bounds__(256) void k_gemm1(const float* __restrict__ x,
                                               const float* __restrict__ W1,
                                               const float* __restrict__ dinv,
                                               __half* __restrict__ h16) {
    const int wave = (blockIdx.x * 256 + threadIdx.x) >> 6;   // tile id
    const int lane = threadIdx.x & 63;
    const int m16 = lane & 15;
    const int quad = lane >> 4;
    if (wave * 16 >= N_NODES) return;

    f16x8 bf[4];
    #pragma unroll
    for (int kb = 0; kb < 4; ++kb)
        #pragma unroll
        for (int j = 0; j < 8; ++j)
            bf[kb][j] = (_Float16)W1[(kb * 32 + quad * 8 + j) * HIDDEN + m16];

    const int node0 = wave * 16;
    const float* xrow = x + (size_t)(node0 + m16) * IN_FEAT + quad * 8;
    f32x4 acc = {0.f, 0.f, 0.f, 0.f};
    #pragma unroll
    for (int kb = 0; kb < 4; ++kb) {
        const v4f* p = (const v4f*)(xrow + kb * 32);
        v4f u0 = p[0], u1 = p[1];
        f16x8 af;
        af[0] = (_Float16)u0.x; af[1] = (_Float16)u0.y;
        af[2] = (_Float16)u0.z; af[3] = (_Float16)u0.w;
        af[4] = (_Float16)u1.x; af[5] = (_Float16)u1.y;
        af[6] = (_Float16)u1.z; af[7] = (_Float16)u1.w;
        acc = __builtin_amdgcn_mfma_f32_16x16x32_f16(af, bf[kb], acc, 0, 0, 0);
    }
    #pragma unroll
    for (int r = 0; r < 4; ++r) {
        int node = node0 + quad * 4 + r;
        h16[(size_t)node * HIDDEN + m16] = __float2half(dinv[node] * acc[r]);
    }
}

// ---------------- layer-1 flat edge scatter, packed-f16 atomics ----------------

__global__ __launch_bounds__(256) void k_scat1(const int* __restrict__ row,
                                               const int* __restrict__ col,
                                               const unsigned* __restrict__ h16u,
                                               __half2* __restrict__ agg) {
    long long tid = (long long)blockIdx.x * 256 + threadIdx.x;
    long long e = tid >> 3;
    int l = (int)(tid & 7);
    if (e >= N_EDGES) return;
    int r = row[e], c = col[e];
    unsigned v = h16u[(size_t)r * 8 + l];
    unsafeAtomicAdd(&agg[(size_t)c * 8 + l], *(const __half2*)&v);
}

// ---------------- fused self-loop + bias + relu + W2 + dinv -> t' ----------------

__global__ __launch_bounds__(256) void k_node2(const __half* __restrict__ aggh,
                                               const __half* __restrict__ h16,
                                               const float* __restrict__ dinv,
                                               const float* __restrict__ b1,
                                               const float* __restrict__ W2,
                                               float* __restrict__ tp) {
    int tid = blockIdx.x * blockDim.x + threadIdx.x;
    int i = tid >> 4, f = tid & 15;
    if (i >= N_NODES) return;
    float di = dinv[i];
    float pre = di * (__half2float(aggh[(size_t)i * HIDDEN + f])
                      + __half2float(h16[(size_t)i * HIDDEN + f]));
    float r = fmaxf(pre + b1[f], 0.f) * W2[f];
    r += __shfl_xor(r, 8, 16);
    r += __shfl_xor(r, 4, 16);
    r += __shfl_xor(r, 2, 16);
    r += __shfl_xor(r, 1, 16);
    if (f == 0) tp[i] = di * r;          // t' = dinv * t
}

// ======== layer-2 aggregation: 13 ranges x 16384 f32 LDS histogram ========
#define ORN 16384
#define ONR 13                // 13*16384 = 212992 >= N_NODES
#define OB  32
#define OEPB (N_EDGES / OB)   // 200000

__global__ __launch_bounds__(256) void k_hist_out(const int* __restrict__ col,
                                                  const int* __restrict__ row,
                                                  const float* __restrict__ tp,
                                                  float* __restrict__ agg2) {
    __shared__ float hs[ORN];             // 64 KB
    const int range = blockIdx.x >> 5;
    const int chunk = blockIdx.x & 31;
    const unsigned lo = range * ORN;
    for (int i = threadIdx.x; i < ORN; i += 256) hs[i] = 0.f;
    __syncthreads();
    const int4* c4 = (const int4*)(col + (size_t)chunk * OEPB);
    const int4* r4 = (const int4*)(row + (size_t)chunk * OEPB);
    const int n4 = OEPB / 4;              // 50000
    for (int i = threadIdx.x; i < n4; i += 256) {
        int4 v = c4[i];
        unsigned a0 = (unsigned)v.x - lo, a1 = (unsigned)v.y - lo;
        unsigned a2 = (unsigned)v.z - lo, a3 = (unsigned)v.w - lo;
        if ((a0 < ORN) || (a1 < ORN) || (a2 < ORN) || (a3 < ORN)) {
            int4 r = r4[i];
            if (a0 < ORN) unsafeAtomicAdd(&hs[a0], tp[r.x]);
            if (a1 < ORN) unsafeAtomicAdd(&hs[a1], tp[r.y]);
            if (a2 < ORN) unsafeAtomicAdd(&hs[a2], tp[r.z]);
            if (a3 < ORN) unsafeAtomicAdd(&hs[a3], tp[r.w]);
        }
    }
    __syncthreads();
    for (int i = threadIdx.x; i < ORN; i += 256) {   // contiguous merge
        unsigned node = lo + i;
        if (node < N_NODES) unsafeAtomicAdd(&agg2[node], hs[i]);
    }
}

// ---------------- finalize: out = b2 + dinv*(t'_self + agg2) ----------------

__global__ void k_fin(const float* __restrict__ tp, const float* __restrict__ agg2,
                      const float* __restrict__ dinv, const float* __restrict__ b2,
                      float* __restrict__ out) {
    int i = blockIdx.x * blockDim.x + threadIdx.x;
    if (i < N_NODES) out[i] = fmaf(dinv[i], tp[i] + agg2[i], b2[0]);
}

// ---------------- launch ----------------

extern "C" void kernel_launch(void* const* d_in, const int* in_sizes, int n_in,
                              void* d_out, int out_size, void* d_ws, size_t ws_size,
                              hipStream_t stream) {
    const float* x   = (const float*)d_in[0];
    const int*   ei  = (const int*)d_in[1];
    const float* W1  = (const float*)d_in[2];
    const float* b1  = (const float*)d_in[3];
    const float* W2  = (const float*)d_in[4];
    const float* b2  = (const float*)d_in[5];
    float* out = (float*)d_out;

    const int* row = ei;               // sources
    const int* col = ei + N_EDGES;     // targets

    // ws zeroed prefix: [cnt u32 N][agg2 f32 N][agg fp16 16N = 8N u32]  (10N u32 = 8 MB)
    // then: [dinv f32 N][tp f32 N][h16 fp16 16N]
    unsigned* cnt  = (unsigned*)d_ws;
    float*    agg2 = (float*)(cnt + N_NODES);
    __half2*  agg  = (__half2*)(agg2 + N_NODES);           // 8 half2 per node
    float*    dinv = (float*)((unsigned*)agg + (size_t)N_NODES * 8);
    float*    tp   = dinv + N_NODES;
    __half*   h16  = (__half*)(tp + N_NODES);

    const int B = 256;
    const int gN   = (N_NODES + B - 1) / B;
    const int gE8  = (int)(((long long)N_EDGES * 8 + B - 1) / B);
    const int gN16 = (N_NODES * 16 + B - 1) / B;

    (void)hipMemsetAsync(cnt, 0, (size_t)N_NODES * 10 * sizeof(unsigned), stream);
    k_hist_cnt<<<CNR * CB, B, 0, stream>>>(col, cnt);
    k_dinv<<<gN, B, 0, stream>>>(cnt, dinv);

    k_gemm1<<<(N_NODES / 16 + 3) / 4, B, 0, stream>>>(x, W1, dinv, h16);
    k_scat1<<<gE8, B, 0, stream>>>(row, col, (const unsigned*)h16, agg);
    k_node2<<<gN16, B, 0, stream>>>((const __half*)agg, h16, dinv, b1, W2, tp);
    k_hist_out<<<ONR * OB, B, 0, stream>>>(col, row, tp, agg2);
    k_fin<<<gN, B, 0, stream>>>(tp, agg2, dinv, b2, out);
}

// Round 10
// 727.584 us; speedup vs baseline: 2.0878x; 1.1596x over previous
//
#include <hip/hip_runtime.h>
#include <hip/hip_fp16.h>

#define N_NODES 200000
#define N_EDGES 6400000
#define IN_FEAT 128
#define HIDDEN  16

typedef float v4f __attribute__((ext_vector_type(4)));
typedef _Float16 f16x8 __attribute__((ext_vector_type(8)));
typedef float f32x4 __attribute__((ext_vector_type(4)));

// ======== degree histogram: 7 ranges x 32768 nodes, u16-packed LDS & global ========
#define CRN 32768
#define CNR 7                 // 7*32768 = 229376 >= N_NODES
#define CB  64                // blocks per range
#define CEPB (N_EDGES / CB)   // 100000 edges per block

__global__ __launch_bounds__(256) void k_hist_cnt(const int* __restrict__ col,
                                                  unsigned* __restrict__ cnt16) {
    __shared__ unsigned hs[CRN / 2];          // 64 KB: 2 x u16 counters per entry
    const int range = blockIdx.x / CB;
    const int chunk = blockIdx.x % CB;
    const unsigned lo = range * CRN;
    for (int i = threadIdx.x; i < CRN / 2; i += 256) hs[i] = 0u;
    __syncthreads();
    const int4* c4 = (const int4*)(col + (size_t)chunk * CEPB);
    const int n4 = CEPB / 4;                  // 25000
    for (int i = threadIdx.x * 2; i < n4; i += 512) {   // 2 int4 in flight
        int4 v0 = c4[i];
        int4 v1 = c4[i + 1];
        unsigned a;
        a = (unsigned)v0.x - lo; if (a < CRN) atomicAdd(&hs[a >> 1], 1u << ((a & 1) * 16));
        a = (unsigned)v0.y - lo; if (a < CRN) atomicAdd(&hs[a >> 1], 1u << ((a & 1) * 16));
        a = (unsigned)v0.z - lo; if (a < CRN) atomicAdd(&hs[a >> 1], 1u << ((a & 1) * 16));
        a = (unsigned)v0.w - lo; if (a < CRN) atomicAdd(&hs[a >> 1], 1u << ((a & 1) * 16));
        a = (unsigned)v1.x - lo; if (a < CRN) atomicAdd(&hs[a >> 1], 1u << ((a & 1) * 16));
        a = (unsigned)v1.y - lo; if (a < CRN) atomicAdd(&hs[a >> 1], 1u << ((a & 1) * 16));
        a = (unsigned)v1.z - lo; if (a < CRN) atomicAdd(&hs[a >> 1], 1u << ((a & 1) * 16));
        a = (unsigned)v1.w - lo; if (a < CRN) atomicAdd(&hs[a >> 1], 1u << ((a & 1) * 16));
    }
    __syncthreads();
    // contiguous merge, u16-pair-packed (no cross-carry: deg << 65536), skip zeros
    const unsigned gbase = lo >> 1;
    for (int i = threadIdx.x; i < CRN / 2; i += 256) {
        unsigned v = hs[i];
        unsigned node = lo + 2 * i;
        if (v && node + 1 < N_NODES) atomicAdd(&cnt16[gbase + i], v);
    }
}

__global__ void k_dinv(const unsigned short* __restrict__ c16, float* __restrict__ dinv) {
    int i = blockIdx.x * blockDim.x + threadIdx.x;
    if (i < N_NODES) dinv[i] = rsqrtf((float)c16[i] + 1.0f);   // +1 self-loop
}

// ---------------- layer-1 GEMM via MFMA: h16 = dinv .* (x @ W1), fp16 ----------------

__global__ __launch_bounds__(256) void k_gemm1(const float* __restrict__ x,
                                               const float* __restrict__ W1,
                                               const float* __restrict__ dinv,
                                               __half* __restrict__ h16) {
    const int wave = (blockIdx.x * 256 + threadIdx.x) >> 6;   // tile id
    const int lane = threadIdx.x & 63;
    const int m16 = lane & 15;
    const int quad = lane >> 4;
    if (wave * 16 >= N_NODES) return;

    f16x8 bf[4];
    #pragma unroll
    for (int kb = 0; kb < 4; ++kb)
        #pragma unroll
        for (int j = 0; j < 8; ++j)
            bf[kb][j] = (_Float16)W1[(kb * 32 + quad * 8 + j) * HIDDEN + m16];

    const int node0 = wave * 16;
    const float* xrow = x + (size_t)(node0 + m16) * IN_FEAT + quad * 8;
    f32x4 acc = {0.f, 0.f, 0.f, 0.f};
    #pragma unroll
    for (int kb = 0; kb < 4; ++kb) {
        const v4f* p = (const v4f*)(xrow + kb * 32);
        v4f u0 = p[0], u1 = p[1];
        f16x8 af;
        af[0] = (_Float16)u0.x; af[1] = (_Float16)u0.y;
        af[2] = (_Float16)u0.z; af[3] = (_Float16)u0.w;
        af[4] = (_Float16)u1.x; af[5] = (_Float16)u1.y;
        af[6] = (_Float16)u1.z; af[7] = (_Float16)u1.w;
        acc = __builtin_amdgcn_mfma_f32_16x16x32_f16(af, bf[kb], acc, 0, 0, 0);
    }
    #pragma unroll
    for (int r = 0; r < 4; ++r) {
        int node = node0 + quad * 4 + r;
        h16[(size_t)node * HIDDEN + m16] = __float2half(dinv[node] * acc[r]);
    }
}

// ---------------- layer-1 flat edge scatter, packed-f16 atomics ----------------

__global__ __launch_bounds__(256) void k_scat1(const int* __restrict__ row,
                                               const int* __restrict__ col,
                                               const unsigned* __restrict__ h16u,
                                               __half2* __restrict__ agg) {
    long long tid = (long long)blockIdx.x * 256 + threadIdx.x;
    long long e = tid >> 3;
    int l = (int)(tid & 7);
    if (e >= N_EDGES) return;
    int r = row[e], c = col[e];
    unsigned v = h16u[(size_t)r * 8 + l];
    unsafeAtomicAdd(&agg[(size_t)c * 8 + l], *(const __half2*)&v);
}

// ---------------- fused self-loop + bias + relu + W2 + dinv -> t' ----------------

__global__ __launch_bounds__(256) void k_node2(const __half* __restrict__ aggh,
                                               const __half* __restrict__ h16,
                                               const float* __restrict__ dinv,
                                               const float* __restrict__ b1,
                                               const float* __restrict__ W2,
                                               float* __restrict__ tp) {
    int tid = blockIdx.x * blockDim.x + threadIdx.x;
    int i = tid >> 4, f = tid & 15;
    if (i >= N_NODES) return;
    float di = dinv[i];
    float pre = di * (__half2float(aggh[(size_t)i * HIDDEN + f])
                      + __half2float(h16[(size_t)i * HIDDEN + f]));
    float r = fmaxf(pre + b1[f], 0.f) * W2[f];
    r += __shfl_xor(r, 8, 16);
    r += __shfl_xor(r, 4, 16);
    r += __shfl_xor(r, 2, 16);
    r += __shfl_xor(r, 1, 16);
    if (f == 0) tp[i] = di * r;          // t' = dinv * t
}

// ======== layer-2 aggregation: 13 ranges x 16384 f32 LDS histogram ========
#define ORN 16384
#define ONR 13                // 13*16384 = 212992 >= N_NODES
#define OB  64
#define OEPB (N_EDGES / OB)   // 100000

__global__ __launch_bounds__(256) void k_hist_out(const int* __restrict__ col,
                                                  const int* __restrict__ row,
                                                  const float* __restrict__ tp,
                                                  float* __restrict__ agg2) {
    __shared__ float hs[ORN];             // 64 KB
    const int range = blockIdx.x / OB;
    const int chunk = blockIdx.x % OB;
    const unsigned lo = range * ORN;
    for (int i = threadIdx.x; i < ORN; i += 256) hs[i] = 0.f;
    __syncthreads();
    const int4* c4 = (const int4*)(col + (size_t)chunk * OEPB);
    const int4* r4 = (const int4*)(row + (size_t)chunk * OEPB);
    const int n4 = OEPB / 4;              // 25000
    for (int i = threadIdx.x * 2; i < n4; i += 512) {   // 2 int4 pairs in flight
        int4 v0 = c4[i];
        int4 r0 = r4[i];
        int4 v1 = c4[i + 1];
        int4 r1 = r4[i + 1];
        unsigned a;
        a = (unsigned)v0.x - lo; if (a < ORN) unsafeAtomicAdd(&hs[a], tp[r0.x]);
        a = (unsigned)v0.y - lo; if (a < ORN) unsafeAtomicAdd(&hs[a], tp[r0.y]);
        a = (unsigned)v0.z - lo; if (a < ORN) unsafeAtomicAdd(&hs[a], tp[r0.z]);
        a = (unsigned)v0.w - lo; if (a < ORN) unsafeAtomicAdd(&hs[a], tp[r0.w]);
        a = (unsigned)v1.x - lo; if (a < ORN) unsafeAtomicAdd(&hs[a], tp[r1.x]);
        a = (unsigned)v1.y - lo; if (a < ORN) unsafeAtomicAdd(&hs[a], tp[r1.y]);
        a = (unsigned)v1.z - lo; if (a < ORN) unsafeAtomicAdd(&hs[a], tp[r1.z]);
        a = (unsigned)v1.w - lo; if (a < ORN) unsafeAtomicAdd(&hs[a], tp[r1.w]);
    }
    __syncthreads();
    for (int i = threadIdx.x; i < ORN; i += 256) {   // contiguous merge, skip zeros
        float v = hs[i];
        unsigned node = lo + i;
        if (v != 0.f && node < N_NODES) unsafeAtomicAdd(&agg2[node], v);
    }
}

// ---------------- finalize: out = b2 + dinv*(t'_self + agg2) ----------------

__global__ void k_fin(const float* __restrict__ tp, const float* __restrict__ agg2,
                      const float* __restrict__ dinv, const float* __restrict__ b2,
                      float* __restrict__ out) {
    int i = blockIdx.x * blockDim.x + threadIdx.x;
    if (i < N_NODES) out[i] = fmaf(dinv[i], tp[i] + agg2[i], b2[0]);
}

// ---------------- launch ----------------

extern "C" void kernel_launch(void* const* d_in, const int* in_sizes, int n_in,
                              void* d_out, int out_size, void* d_ws, size_t ws_size,
                              hipStream_t stream) {
    const float* x   = (const float*)d_in[0];
    const int*   ei  = (const int*)d_in[1];
    const float* W1  = (const float*)d_in[2];
    const float* b1  = (const float*)d_in[3];
    const float* W2  = (const float*)d_in[4];
    const float* b2  = (const float*)d_in[5];
    float* out = (float*)d_out;

    const int* row = ei;               // sources
    const int* col = ei + N_EDGES;     // targets

    // ws zeroed prefix: [cnt16 u32 N/2][agg2 f32 N][agg fp16 16N = 8N u32] (9.5N u32 = 7.6 MB)
    // then: [dinv f32 N][tp f32 N][h16 fp16 16N]
    unsigned* cnt16 = (unsigned*)d_ws;
    float*    agg2  = (float*)(cnt16 + N_NODES / 2);
    __half2*  agg   = (__half2*)(agg2 + N_NODES);          // 8 half2 per node
    float*    dinv  = (float*)((unsigned*)agg + (size_t)N_NODES * 8);
    float*    tp    = dinv + N_NODES;
    __half*   h16   = (__half*)(tp + N_NODES);

    const int B = 256;
    const int gN   = (N_NODES + B - 1) / B;
    const int gE8  = (int)(((long long)N_EDGES * 8 + B - 1) / B);
    const int gN16 = (N_NODES * 16 + B - 1) / B;

    (void)hipMemsetAsync(cnt16, 0, (size_t)(N_NODES / 2 + N_NODES * 9) * sizeof(unsigned), stream);
    k_hist_cnt<<<CNR * CB, B, 0, stream>>>(col, cnt16);
    k_dinv<<<gN, B, 0, stream>>>((const unsigned short*)cnt16, dinv);

    k_gemm1<<<(N_NODES / 16 + 3) / 4, B, 0, stream>>>(x, W1, dinv, h16);
    k_scat1<<<gE8, B, 0, stream>>>(row, col, (const unsigned*)h16, agg);
    k_node2<<<gN16, B, 0, stream>>>((const __half*)agg, h16, dinv, b1, W2, tp);
    k_hist_out<<<ONR * OB, B, 0, stream>>>(col, row, tp, agg2);
    k_fin<<<gN, B, 0, stream>>>(tp, agg2, dinv, b2, out);
}